// Round 12
// baseline (141.833 us; speedup 1.0000x reference)
//
#include <hip/hip_runtime.h>
#include <stdint.h>

#define B_ 2
#define L_ 2048
#define DM 1024
#define NH 16
#define DH 64
#define M_ (B_*L_)     // 4096

typedef short short8 __attribute__((ext_vector_type(8)));
typedef float f32x4 __attribute__((ext_vector_type(4)));

__device__ __forceinline__ unsigned short f2b(float f) {
    union { float f; unsigned int u; } v; v.f = f;
    unsigned int u = v.u;
    return (unsigned short)((u + 0x7fffu + ((u >> 16) & 1u)) >> 16);   // RNE
}

__device__ __forceinline__ void gld_lds16(const void* g, void* l) {
    __builtin_amdgcn_global_load_lds(
        (const __attribute__((address_space(1))) void*)g,
        (__attribute__((address_space(3))) void*)l, 16, 0, 0);
}

// ---------------- fused setup (round-0 proven) -------------------------------
__global__ __launch_bounds__(256)
void setup_kernel(const float* __restrict__ x,
                  const float* __restrict__ Wq, const float* __restrict__ Wk,
                  const float* __restrict__ Wv, const float* __restrict__ Wo,
                  const float* __restrict__ bq, const float* __restrict__ bk,
                  const float* __restrict__ bv,
                  unsigned short* __restrict__ xb, unsigned short* __restrict__ WqkvT,
                  unsigned short* __restrict__ WoT, float* __restrict__ biasq,
                  float* __restrict__ KtV)
{
    __shared__ float tile[32][33];
    const int bid = blockIdx.x;
    const int t = threadIdx.x;

    if (bid < 2048) {
        int i = (bid * 256 + t) * 8;
        float4 a0 = *(const float4*)(x + i);
        float4 a1 = *(const float4*)(x + i + 4);
        uint4 p;
        p.x = (unsigned)f2b(a0.x) | ((unsigned)f2b(a0.y) << 16);
        p.y = (unsigned)f2b(a0.z) | ((unsigned)f2b(a0.w) << 16);
        p.z = (unsigned)f2b(a1.x) | ((unsigned)f2b(a1.y) << 16);
        p.w = (unsigned)f2b(a1.z) | ((unsigned)f2b(a1.w) << 16);
        *(uint4*)(xb + i) = p;
    } else if (bid < 2048 + 4096) {
        int wb = bid - 2048;
        int wi = wb >> 10;                // 0=Wq 1=Wk 2=Wv 3=Wo
        int tid = wb & 1023;
        const float* W = (wi == 0) ? Wq : (wi == 1) ? Wk : (wi == 2) ? Wv : Wo;
        float s = (wi == 1) ? 0.125f : 1.0f;
        int n0 = (tid & 31) * 32, k0 = (tid >> 5) * 32;
        int r = t >> 3, c4 = (t & 7) << 2;
        float4 v = *(const float4*)(W + (size_t)(k0 + r) * DM + n0 + c4);
        tile[r][c4+0] = v.x; tile[r][c4+1] = v.y; tile[r][c4+2] = v.z; tile[r][c4+3] = v.w;
        __syncthreads();
        uint2 o;
        o.x = (unsigned)f2b(tile[c4+0][r]*s) | ((unsigned)f2b(tile[c4+1][r]*s) << 16);
        o.y = (unsigned)f2b(tile[c4+2][r]*s) | ((unsigned)f2b(tile[c4+3][r]*s) << 16);
        int f = n0 + r;
        size_t drow;
        unsigned short* dst;
        if (wi == 0)      { dst = WqkvT; drow = f; }
        else if (wi == 1) { dst = WqkvT; drow = 1024 + (f >> 6) * 128 + (f & 63); }
        else if (wi == 2) { dst = WqkvT; drow = 1024 + (f >> 6) * 128 + 64 + (f & 63); }
        else              { dst = WoT;   drow = f; }
        *(uint2*)(dst + drow * DM + k0 + c4) = o;
    } else if (bid < 2048 + 4096 + 12) {
        int n = (bid - 6144) * 256 + t;
        float v;
        if (n < 1024) v = bq[n];
        else {
            int kv = (n - 1024) >> 7, r = (n - 1024) & 127;
            v = (r < 64) ? 0.125f * bk[kv * 64 + r] : bv[kv * 64 + (r - 64)];
        }
        biasq[n] = v;
    } else {
        int i = ((bid - 6156) * 256 + t) * 4;
        float4 z; z.x = z.y = z.z = z.w = 0.f;
        *(float4*)(KtV + i) = z;
    }
}

// ---- QKV projection: 256x256 tile, 8 waves, BK=32, 4-buffer depth-3 pipeline -
// grid: 192 blocks (mt 0..15, nt 0..11). nt<4 -> Q cols; nt>=4 -> 2 heads/tile
__global__ __launch_bounds__(512, 2)
void qkv_fused_kernel(const unsigned short* __restrict__ A,
                      const unsigned short* __restrict__ Bt,
                      const float* __restrict__ biasq,
                      unsigned short* __restrict__ Qb,
                      float* __restrict__ KtV)
{
    __shared__ __align__(16) char smem[131072];
    // buffers 0..3 at b*32768: A-tile 256x32 bf16 (16 KB) + B-tile (16 KB)
    // after K-loop: Xt overlay uses all 128 KB (KV blocks only)

    const int bid = blockIdx.x;
    const int mt = bid & 15;          // 0..15
    const int nt = bid >> 4;          // 0..11
    const int m0 = mt * 256, n0 = nt * 256;

    const int t = threadIdx.x;        // 0..511
    const int w = t >> 6, lane = t & 63;
    const int quad = lane >> 4, l16 = lane & 15;
    const int wr = w >> 2, wc = w & 3;   // wave output: rows wr*128+, cols wc*64+

    f32x4 acc[8][4];
    #pragma unroll
    for (int i = 0; i < 8; i++)
        #pragma unroll
        for (int j = 0; j < 4; j++)
            #pragma unroll
            for (int r = 0; r < 4; r++) acc[i][j][r] = 0.f;

    // per-thread staging map: 2 gld per matrix per tile
    const int c0 = t, c1 = 512 + t;
    const int row0 = c0 >> 2, g0 = (c0 & 3) ^ ((row0 >> 1) & 3);
    const int row1 = c1 >> 2, g1 = (c1 & 3) ^ ((row1 >> 1) & 3);

    auto STAGE_A = [&](int buf, int kk) {
        gld_lds16(A + (size_t)(m0 + row0) * DM + kk + g0 * 8,
                  smem + buf * 32768 + w * 1024);
        gld_lds16(A + (size_t)(m0 + row1) * DM + kk + g1 * 8,
                  smem + buf * 32768 + 8192 + w * 1024);
    };
    auto STAGE_B = [&](int buf, int kk) {
        gld_lds16(Bt + (size_t)(n0 + row0) * DM + kk + g0 * 8,
                  smem + buf * 32768 + 16384 + w * 1024);
        gld_lds16(Bt + (size_t)(n0 + row1) * DM + kk + g1 * 8,
                  smem + buf * 32768 + 16384 + 8192 + w * 1024);
    };

    short8 bf[4], af[4];
    auto COMPUTE_FULL = [&](const char* Ab) {
        const char* Bb = Ab + 16384;
        #pragma unroll
        for (int j = 0; j < 4; j++) {
            int bn = wc * 64 + j * 16 + l16;
            bf[j] = *(const short8*)(Bb + bn * 64 + ((quad ^ ((bn >> 1) & 3)) << 4));
        }
        #pragma unroll
        for (int i = 0; i < 4; i++) {
            int am = wr * 128 + i * 16 + l16;
            af[i] = *(const short8*)(Ab + am * 64 + ((quad ^ ((am >> 1) & 3)) << 4));
        }
        __builtin_amdgcn_s_setprio(1);
        #pragma unroll
        for (int i = 0; i < 4; i++)
            #pragma unroll
            for (int j = 0; j < 4; j++)
                acc[i][j] = __builtin_amdgcn_mfma_f32_16x16x32_bf16(af[i], bf[j], acc[i][j], 0, 0, 0);
        __builtin_amdgcn_s_setprio(0);
        #pragma unroll
        for (int i = 0; i < 4; i++) {
            int am = wr * 128 + (i + 4) * 16 + l16;
            af[i] = *(const short8*)(Ab + am * 64 + ((quad ^ ((am >> 1) & 3)) << 4));
        }
        __builtin_amdgcn_s_setprio(1);
        #pragma unroll
        for (int i = 0; i < 4; i++)
            #pragma unroll
            for (int j = 0; j < 4; j++)
                acc[i + 4][j] = __builtin_amdgcn_mfma_f32_16x16x32_bf16(af[i], bf[j], acc[i + 4][j], 0, 0, 0);
        __builtin_amdgcn_s_setprio(0);
    };

    // prologue: tiles 0,1,2 in flight (12 loads/thread)
    STAGE_A(0, 0);   STAGE_B(0, 0);
    STAGE_A(1, 32);  STAGE_B(1, 32);
    STAGE_A(2, 64);  STAGE_B(2, 64);

    int cur = 0, st = 3;

    // tiles 0..29: entry has 12 outstanding, vmcnt(8) drains tile T exactly;
    // stage tile T+3 (tiles 3..31) while T<29; buf (T+3)%4 last read at T-1,
    // protected by this tile's entry barrier.
    for (int T = 0; T < 30; T++) {
        asm volatile("s_waitcnt vmcnt(8)" ::: "memory");
        __builtin_amdgcn_sched_barrier(0);
        __builtin_amdgcn_s_barrier();
        __builtin_amdgcn_sched_barrier(0);

        const char* Ab = smem + cur * 32768;
        const char* Bb = Ab + 16384;

        // phase 0: stage A(T+3), read af0-3 + bf0-3, 16 MFMA
        if (T < 29) STAGE_A(st, (T + 3) * 32);
        #pragma unroll
        for (int j = 0; j < 4; j++) {
            int bn = wc * 64 + j * 16 + l16;
            bf[j] = *(const short8*)(Bb + bn * 64 + ((quad ^ ((bn >> 1) & 3)) << 4));
        }
        #pragma unroll
        for (int i = 0; i < 4; i++) {
            int am = wr * 128 + i * 16 + l16;
            af[i] = *(const short8*)(Ab + am * 64 + ((quad ^ ((am >> 1) & 3)) << 4));
        }
        __builtin_amdgcn_s_setprio(1);
        #pragma unroll
        for (int i = 0; i < 4; i++)
            #pragma unroll
            for (int j = 0; j < 4; j++)
                acc[i][j] = __builtin_amdgcn_mfma_f32_16x16x32_bf16(af[i], bf[j], acc[i][j], 0, 0, 0);
        __builtin_amdgcn_s_setprio(0);

        // phase 1: stage B(T+3), read af4-7, 16 MFMA
        if (T < 29) STAGE_B(st, (T + 3) * 32);
        #pragma unroll
        for (int i = 0; i < 4; i++) {
            int am = wr * 128 + (i + 4) * 16 + l16;
            af[i] = *(const short8*)(Ab + am * 64 + ((quad ^ ((am >> 1) & 3)) << 4));
        }
        __builtin_amdgcn_s_setprio(1);
        #pragma unroll
        for (int i = 0; i < 4; i++)
            #pragma unroll
            for (int j = 0; j < 4; j++)
                acc[i + 4][j] = __builtin_amdgcn_mfma_f32_16x16x32_bf16(af[i], bf[j], acc[i + 4][j], 0, 0, 0);
        __builtin_amdgcn_s_setprio(0);

        cur = (cur + 1) & 3;
        st  = (st + 1) & 3;
    }

    // tile 30 (buf 2): 8 outstanding -> vmcnt(4) drains tile 30
    asm volatile("s_waitcnt vmcnt(4)" ::: "memory");
    __builtin_amdgcn_sched_barrier(0);
    __builtin_amdgcn_s_barrier();
    __builtin_amdgcn_sched_barrier(0);
    COMPUTE_FULL(smem + cur * 32768);
    cur = (cur + 1) & 3;

    // tile 31 (buf 3): drain all
    asm volatile("s_waitcnt vmcnt(0)" ::: "memory");
    __builtin_amdgcn_sched_barrier(0);
    __builtin_amdgcn_s_barrier();
    __builtin_amdgcn_sched_barrier(0);
    COMPUTE_FULL(smem + cur * 32768);

    #pragma unroll
    for (int j = 0; j < 4; j++) {
        float bv = biasq[n0 + wc * 64 + j * 16 + l16];
        #pragma unroll
        for (int i = 0; i < 8; i++)
            #pragma unroll
            for (int r = 0; r < 4; r++) acc[i][j][r] += bv;
    }

    if (nt < 4) {
        #pragma unroll
        for (int j = 0; j < 4; j++) {
            int col = n0 + wc * 64 + j * 16 + l16;
            #pragma unroll
            for (int i = 0; i < 8; i++) {
                #pragma unroll
                for (int r = 0; r < 4; r++) {
                    int row = m0 + wr * 128 + i * 16 + quad * 4 + r;
                    Qb[(size_t)row * DM + col] = f2b(acc[i][j][r]);
                }
            }
        }
        return;
    }

    // ---- KV region (round-5/8 verified): cols [0,128)=head 2*(nt-4), [128,256)=+1
    // Xt overlay: col c (0..255) at byte c*512, row l at byte (l*2)^((c&7)<<4)
    __builtin_amdgcn_sched_barrier(0);
    __builtin_amdgcn_s_barrier();        // all waves done with staging buffers

    #pragma unroll
    for (int j = 0; j < 4; j++) {
        int c = wc * 64 + j * 16 + l16;
        int cs = (c & 7) << 4;
        #pragma unroll
        for (int i = 0; i < 8; i++) {
            int l0 = wr * 128 + i * 16 + quad * 4;
            uint2 o;
            o.x = (unsigned)f2b(acc[i][j][0]) | ((unsigned)f2b(acc[i][j][1]) << 16);
            o.y = (unsigned)f2b(acc[i][j][2]) | ((unsigned)f2b(acc[i][j][3]) << 16);
            *(uint2*)(smem + c * 512 + ((l0 * 2) ^ cs)) = o;
        }
    }
    __builtin_amdgcn_sched_barrier(0);
    __builtin_amdgcn_s_barrier();

    const int hh = w >> 2;            // head within tile (0,1)
    const int s  = w & 3;             // d1 slice (16 rows each)
    const int bb = mt >> 3;
    const int h  = (nt - 4) * 2 + hh;

    f32x4 kacc[4];
    #pragma unroll
    for (int j = 0; j < 4; j++)
        #pragma unroll
        for (int r = 0; r < 4; r++) kacc[j][r] = 0.f;

    #pragma unroll
    for (int ks = 0; ks < 8; ks++) {
        int ca = hh * 128 + s * 16 + l16;
        short8 afk = *(const short8*)(smem + ca * 512 + ((ks * 64 + quad * 16) ^ ((ca & 7) << 4)));
        #pragma unroll
        for (int j = 0; j < 4; j++) {
            int cb = hh * 128 + 64 + j * 16 + l16;
            short8 bfk = *(const short8*)(smem + cb * 512 + ((ks * 64 + quad * 16) ^ ((cb & 7) << 4)));
            kacc[j] = __builtin_amdgcn_mfma_f32_16x16x32_bf16(afk, bfk, kacc[j], 0, 0, 0);
        }
    }

    float* dst = KtV + (size_t)(bb * NH + h) * 64 * 64;
    #pragma unroll
    for (int j = 0; j < 4; j++) {
        int col = j * 16 + l16;
        #pragma unroll
        for (int r = 0; r < 4; r++) {
            int row = s * 16 + quad * 4 + r;
            atomicAdd(dst + row * 64 + col, kacc[j][r]);
        }
    }
}

// ---------------- ZT[b][n][h*64+d1] = sum_d2 KtV[bh][d1][d2]*WoT[n][h*64+d2] --
__global__ __launch_bounds__(256)
void zmat_kernel(const unsigned short* __restrict__ WoT, const float* __restrict__ KtV,
                 unsigned short* __restrict__ ZT)
{
    __shared__ __align__(16) unsigned short Asl[64][72];  // [n][d2]
    __shared__ __align__(16) unsigned short Bsl[64][72];  // [d1][d2]

    const int bh = blockIdx.x, nt0 = blockIdx.y;
    const int b = bh >> 4, h = bh & 15;
    const int t = threadIdx.x;
    const int wave = t >> 6, lane = t & 63;
    const int quad = lane >> 4, l16 = lane & 15;
    const int n0 = nt0 * 64;
    const int row = t >> 2, c0 = (t & 3) << 4;

    const unsigned short* ap = WoT + (size_t)(n0 + row) * DM + h * DH + c0;
    *(uint4*)&Asl[row][c0]     = *(const uint4*)ap;
    *(uint4*)&Asl[row][c0 + 8] = *(const uint4*)(ap + 8);

    const float* kp = KtV + ((size_t)bh * 64 + row) * 64 + c0;
    #pragma unroll
    for (int j = 0; j < 16; j++) Bsl[row][c0 + j] = f2b(kp[j]);
    __syncthreads();

    f32x4 acc[4];
    #pragma unroll
    for (int i = 0; i < 4; i++)
        #pragma unroll
        for (int r = 0; r < 4; r++) acc[i][r] = 0.f;

    #pragma unroll
    for (int ks = 0; ks < 2; ks++) {
        short8 af = *(const short8*)&Asl[wave * 16 + l16][ks * 32 + quad * 8];
        #pragma unroll
        for (int nt = 0; nt < 4; nt++) {
            short8 bfr = *(const short8*)&Bsl[nt * 16 + l16][ks * 32 + quad * 8];
            acc[nt] = __builtin_amdgcn_mfma_f32_16x16x32_bf16(af, bfr, acc[nt], 0, 0, 0);
        }
    }

    unsigned short* zb = ZT + (size_t)b * 1024 * 1024 + (size_t)h * DH;
    #pragma unroll
    for (int nt = 0; nt < 4; nt++) {
        int col = nt * 16 + l16;
        #pragma unroll
        for (int r = 0; r < 4; r++) {
            int zr = n0 + wave * 16 + quad * 4 + r;
            zb[(size_t)zr * 1024 + col] = f2b(acc[nt][r]);
        }
    }
}

// ---- out = Q @ ZT[b] + bo: 128x64 tile, BK=64, 3-buffer counted pipeline ----
__global__ __launch_bounds__(256)
void out_gemm_kernel(const unsigned short* __restrict__ A,
                     const unsigned short* __restrict__ Bt,
                     const float* __restrict__ bias,
                     float* __restrict__ C)
{
    __shared__ __align__(16) char smem[73728];
    // buffers 0..2 at b*24576: A-tile 128x64 bf16 (16 KB) + B-tile 64x64 (8 KB)

    const int bid = blockIdx.x;
    const int xcd = bid & 7, local = bid >> 3;   // 64 per XCD
    const int mt = xcd * 4 + (local & 3);        // 0..31
    const int nt = local >> 2;                   // 0..15
    const int m0 = mt * 128, n0 = nt * 64;

    const int t = threadIdx.x;
    const int w = t >> 6, lane = t & 63;
    const int quad = lane >> 4, l16 = lane & 15;

    const unsigned short* Btb = Bt + (size_t)(m0 >> 11) * 1024 * 1024;

    f32x4 acc[2][4];
    #pragma unroll
    for (int i = 0; i < 2; i++)
        #pragma unroll
        for (int j = 0; j < 4; j++)
            #pragma unroll
            for (int r = 0; r < 4; r++) acc[i][j][r] = 0.f;

    auto STAGE = [&](int buf, int kk) {
        #pragma unroll
        for (int p = 0; p < 4; p++) {              // A: 128 rows x 8 chunks
            int c = p * 256 + t;
            int row = c >> 3, slot = c & 7;
            int g = slot ^ ((row >> 1) & 7);
            gld_lds16(A + (size_t)(m0 + row) * DM + kk + g * 8,
                      smem + buf * 24576 + p * 4096 + w * 1024);
        }
        #pragma unroll
        for (int p = 0; p < 2; p++) {              // B: 64 rows x 8 chunks
            int c = p * 256 + t;
            int row = c >> 3, slot = c & 7;
            int g = slot ^ ((row >> 1) & 7);
            gld_lds16(Btb + (size_t)(n0 + row) * DM + kk + g * 8,
                      smem + buf * 24576 + 16384 + p * 4096 + w * 1024);
        }
    };
    auto COMPUTE = [&](int buf) {
        const char* Asb = smem + buf * 24576;
        const char* Bsb = Asb + 16384;
        #pragma unroll
        for (int ks = 0; ks < 2; ks++) {
            int kc = ks * 4 + quad;
            short8 afr[2], bfr[4];
            #pragma unroll
            for (int i = 0; i < 2; i++) {
                int am = w * 32 + i * 16 + l16;
                afr[i] = *(const short8*)(Asb + am * 128 + ((kc ^ ((am >> 1) & 7)) << 4));
            }
            #pragma unroll
            for (int j = 0; j < 4; j++) {
                int bn = j * 16 + l16;
                bfr[j] = *(const short8*)(Bsb + bn * 128 + ((kc ^ ((bn >> 1) & 7)) << 4));
            }
            __builtin_amdgcn_s_setprio(1);
            #pragma unroll
            for (int i = 0; i < 2; i++)
                #pragma unroll
                for (int j = 0; j < 4; j++)
                    acc[i][j] = __builtin_amdgcn_mfma_f32_16x16x32_bf16(afr[i], bfr[j], acc[i][j], 0, 0, 0);
            __builtin_amdgcn_s_setprio(0);
        }
    };

    // prologue: tiles 0,1 in flight (6 loads/thread each)
    STAGE(0, 0);
    STAGE(1, 64);

    int cur = 0, st = 2;
    // 16 K-tiles total: loop T=0..14 (stage tiles 2..15 while T<14), final T=15
    for (int T = 0; T < 15; T++) {
        asm volatile("s_waitcnt vmcnt(6)" ::: "memory");   // tile T landed
        __builtin_amdgcn_sched_barrier(0);
        __builtin_amdgcn_s_barrier();
        __builtin_amdgcn_sched_barrier(0);

        if (T < 14) STAGE(st, (T + 2) * 64);
        COMPUTE(cur);

        cur = (cur == 2) ? 0 : cur + 1;
        st  = (st  == 2) ? 0 : st  + 1;
    }
    // final tile (T=15): cur == 0 here (15 % 3)
    asm volatile("s_waitcnt vmcnt(0)" ::: "memory");
    __builtin_amdgcn_sched_barrier(0);
    __builtin_amdgcn_s_barrier();
    __builtin_amdgcn_sched_barrier(0);
    COMPUTE(cur);

    #pragma unroll
    for (int j = 0; j < 4; j++) {
        int col = n0 + j * 16 + l16;
        float bv = bias[col];
        #pragma unroll
        for (int i = 0; i < 2; i++) {
            #pragma unroll
            for (int r = 0; r < 4; r++) {
                int row = m0 + w * 32 + i * 16 + quad * 4 + r;
                C[(size_t)row * DM + col] = acc[i][j][r] + bv;
            }
        }
    }
}

// ---------------- launch ------------------------------------------------------

extern "C" void kernel_launch(void* const* d_in, const int* in_sizes, int n_in,
                              void* d_out, int out_size, void* d_ws, size_t ws_size,
                              hipStream_t stream)
{
    const float* x  = (const float*)d_in[0];
    const float* Wq = (const float*)d_in[1];
    const float* bq = (const float*)d_in[2];
    const float* Wk = (const float*)d_in[3];
    const float* bk = (const float*)d_in[4];
    const float* Wv = (const float*)d_in[5];
    const float* bv = (const float*)d_in[6];
    const float* Wo = (const float*)d_in[7];
    const float* bo = (const float*)d_in[8];

    char* ws = (char*)d_ws;
    unsigned short* xb    = (unsigned short*)(ws);                              // 8 MB
    unsigned short* WqkvT = (unsigned short*)(ws + (size_t)8  * 1024 * 1024);   // 6 MB
    unsigned short* WoT   = (unsigned short*)(ws + (size_t)14 * 1024 * 1024);   // 2 MB
    float*          biasq = (float*)         (ws + (size_t)16 * 1024 * 1024);   // 12 KB
    unsigned short* Qb    = (unsigned short*)(ws + (size_t)17 * 1024 * 1024);   // 8 MB
    unsigned short* ZT    = (unsigned short*)(ws + (size_t)25 * 1024 * 1024);   // 4 MB
    float*          KtV   = (float*)         (ws + (size_t)29 * 1024 * 1024);   // 512 KB

    setup_kernel<<<6284, 256, 0, stream>>>(x, Wq, Wk, Wv, Wo, bq, bk, bv,
                                           xb, WqkvT, WoT, biasq, KtV);

    qkv_fused_kernel<<<192, 512, 0, stream>>>(xb, WqkvT, biasq, Qb, KtV);

    zmat_kernel<<<dim3(B_ * NH, 16), 256, 0, stream>>>(WoT, KtV, ZT);

    out_gemm_kernel<<<512, 256, 0, stream>>>(Qb, ZT, bo, (float*)d_out);
}

// Round 13
// 141.801 us; speedup vs baseline: 1.0002x; 1.0002x over previous
//
#include <hip/hip_runtime.h>
#include <stdint.h>

#define B_ 2
#define L_ 2048
#define DM 1024
#define NH 16
#define DH 64
#define M_ (B_*L_)     // 4096

typedef short short8 __attribute__((ext_vector_type(8)));
typedef float f32x4 __attribute__((ext_vector_type(4)));

__device__ __forceinline__ unsigned short f2b(float f) {
    union { float f; unsigned int u; } v; v.f = f;
    unsigned int u = v.u;
    return (unsigned short)((u + 0x7fffu + ((u >> 16) & 1u)) >> 16);   // RNE
}

__device__ __forceinline__ void gld_lds16(const void* g, void* l) {
    __builtin_amdgcn_global_load_lds(
        (const __attribute__((address_space(1))) void*)g,
        (__attribute__((address_space(3))) void*)l, 16, 0, 0);
}

// ---------------- fused setup (round-0 proven) -------------------------------
__global__ __launch_bounds__(256)
void setup_kernel(const float* __restrict__ x,
                  const float* __restrict__ Wq, const float* __restrict__ Wk,
                  const float* __restrict__ Wv, const float* __restrict__ Wo,
                  const float* __restrict__ bq, const float* __restrict__ bk,
                  const float* __restrict__ bv,
                  unsigned short* __restrict__ xb, unsigned short* __restrict__ WqkvT,
                  unsigned short* __restrict__ WoT, float* __restrict__ biasq,
                  float* __restrict__ KtV)
{
    __shared__ float tile[32][33];
    const int bid = blockIdx.x;
    const int t = threadIdx.x;

    if (bid < 2048) {
        int i = (bid * 256 + t) * 8;
        float4 a0 = *(const float4*)(x + i);
        float4 a1 = *(const float4*)(x + i + 4);
        uint4 p;
        p.x = (unsigned)f2b(a0.x) | ((unsigned)f2b(a0.y) << 16);
        p.y = (unsigned)f2b(a0.z) | ((unsigned)f2b(a0.w) << 16);
        p.z = (unsigned)f2b(a1.x) | ((unsigned)f2b(a1.y) << 16);
        p.w = (unsigned)f2b(a1.z) | ((unsigned)f2b(a1.w) << 16);
        *(uint4*)(xb + i) = p;
    } else if (bid < 2048 + 4096) {
        int wb = bid - 2048;
        int wi = wb >> 10;                // 0=Wq 1=Wk 2=Wv 3=Wo
        int tid = wb & 1023;
        const float* W = (wi == 0) ? Wq : (wi == 1) ? Wk : (wi == 2) ? Wv : Wo;
        float s = (wi == 1) ? 0.125f : 1.0f;
        int n0 = (tid & 31) * 32, k0 = (tid >> 5) * 32;
        int r = t >> 3, c4 = (t & 7) << 2;
        float4 v = *(const float4*)(W + (size_t)(k0 + r) * DM + n0 + c4);
        tile[r][c4+0] = v.x; tile[r][c4+1] = v.y; tile[r][c4+2] = v.z; tile[r][c4+3] = v.w;
        __syncthreads();
        uint2 o;
        o.x = (unsigned)f2b(tile[c4+0][r]*s) | ((unsigned)f2b(tile[c4+1][r]*s) << 16);
        o.y = (unsigned)f2b(tile[c4+2][r]*s) | ((unsigned)f2b(tile[c4+3][r]*s) << 16);
        int f = n0 + r;
        size_t drow;
        unsigned short* dst;
        if (wi == 0)      { dst = WqkvT; drow = f; }
        else if (wi == 1) { dst = WqkvT; drow = 1024 + (f >> 6) * 128 + (f & 63); }
        else if (wi == 2) { dst = WqkvT; drow = 1024 + (f >> 6) * 128 + 64 + (f & 63); }
        else              { dst = WoT;   drow = f; }
        *(uint2*)(dst + drow * DM + k0 + c4) = o;
    } else if (bid < 2048 + 4096 + 12) {
        int n = (bid - 6144) * 256 + t;
        float v;
        if (n < 1024) v = bq[n];
        else {
            int kv = (n - 1024) >> 7, r = (n - 1024) & 127;
            v = (r < 64) ? 0.125f * bk[kv * 64 + r] : bv[kv * 64 + (r - 64)];
        }
        biasq[n] = v;
    } else {
        int i = ((bid - 6156) * 256 + t) * 4;
        float4 z; z.x = z.y = z.z = z.w = 0.f;
        *(float4*)(KtV + i) = z;
    }
}

// ---- QKV projection: 256x256 tile, 8 waves, BK=32, 3-buffer counted pipeline -
// grid: 192 blocks, XCD-swizzled (bijective: 192 = 8 x 24).
// nt<4 -> Q cols; nt>=4 -> 2 heads/tile
__global__ __launch_bounds__(512, 2)
void qkv_fused_kernel(const unsigned short* __restrict__ A,
                      const unsigned short* __restrict__ Bt,
                      const float* __restrict__ biasq,
                      unsigned short* __restrict__ Qb,
                      float* __restrict__ KtV)
{
    __shared__ __align__(16) char smem[131072];
    // buffers 0..2 at b*32768: A-tile 256x32 bf16 (16 KB) + B-tile (16 KB)
    // after K-loop: Xt overlay uses all 128 KB (KV blocks only)

    const int bid = blockIdx.x;
    // T1 XCD swizzle: XCD k (bids ≡ k mod 8) owns v = k*24 .. k*24+23 —
    // consecutive v share nt (B-panel) -> per-XCD L2 footprint ~8.8 MB vs 14.
    const int v  = (bid & 7) * 24 + (bid >> 3);
    const int mt = v & 15;            // 0..15
    const int nt = v >> 4;            // 0..11
    const int m0 = mt * 256, n0 = nt * 256;

    const int t = threadIdx.x;        // 0..511
    const int w = t >> 6, lane = t & 63;
    const int quad = lane >> 4, l16 = lane & 15;
    const int wr = w >> 2, wc = w & 3;   // wave output: rows wr*128+, cols wc*64+

    f32x4 acc[8][4];
    #pragma unroll
    for (int i = 0; i < 8; i++)
        #pragma unroll
        for (int j = 0; j < 4; j++)
            #pragma unroll
            for (int r = 0; r < 4; r++) acc[i][j][r] = 0.f;

    // per-thread staging map: 2 gld per matrix per tile
    const int c0 = t, c1 = 512 + t;
    const int row0 = c0 >> 2, g0 = (c0 & 3) ^ ((row0 >> 1) & 3);
    const int row1 = c1 >> 2, g1 = (c1 & 3) ^ ((row1 >> 1) & 3);

    auto STAGE_A = [&](int buf, int kk) {
        gld_lds16(A + (size_t)(m0 + row0) * DM + kk + g0 * 8,
                  smem + buf * 32768 + w * 1024);
        gld_lds16(A + (size_t)(m0 + row1) * DM + kk + g1 * 8,
                  smem + buf * 32768 + 8192 + w * 1024);
    };
    auto STAGE_B = [&](int buf, int kk) {
        gld_lds16(Bt + (size_t)(n0 + row0) * DM + kk + g0 * 8,
                  smem + buf * 32768 + 16384 + w * 1024);
        gld_lds16(Bt + (size_t)(n0 + row1) * DM + kk + g1 * 8,
                  smem + buf * 32768 + 16384 + 8192 + w * 1024);
    };

    // prologue: tiles 0,1 in flight (8 loads/thread); wait tile 0 (keep 4)
    STAGE_A(0, 0);  STAGE_B(0, 0);
    STAGE_A(1, 32); STAGE_B(1, 32);

    int cur = 0, st = 2;
    short8 bf[4], af[4];

    for (int T = 0; T < 31; T++) {
        asm volatile("s_waitcnt vmcnt(4)" ::: "memory");
        __builtin_amdgcn_sched_barrier(0);
        __builtin_amdgcn_s_barrier();
        __builtin_amdgcn_sched_barrier(0);

        const char* Ab = smem + cur * 32768;
        const char* Bb = Ab + 16384;

        // phase 0: stage A(T+2), read af0-3 + bf0-3, 16 MFMA
        if (T < 30) STAGE_A(st, (T + 2) * 32);
        #pragma unroll
        for (int j = 0; j < 4; j++) {
            int bn = wc * 64 + j * 16 + l16;
            bf[j] = *(const short8*)(Bb + bn * 64 + ((quad ^ ((bn >> 1) & 3)) << 4));
        }
        #pragma unroll
        for (int i = 0; i < 4; i++) {
            int am = wr * 128 + i * 16 + l16;
            af[i] = *(const short8*)(Ab + am * 64 + ((quad ^ ((am >> 1) & 3)) << 4));
        }
        __builtin_amdgcn_s_setprio(1);
        #pragma unroll
        for (int i = 0; i < 4; i++)
            #pragma unroll
            for (int j = 0; j < 4; j++)
                acc[i][j] = __builtin_amdgcn_mfma_f32_16x16x32_bf16(af[i], bf[j], acc[i][j], 0, 0, 0);
        __builtin_amdgcn_s_setprio(0);

        // phase 1: stage B(T+2), read af4-7, 16 MFMA
        if (T < 30) STAGE_B(st, (T + 2) * 32);
        #pragma unroll
        for (int i = 0; i < 4; i++) {
            int am = wr * 128 + (i + 4) * 16 + l16;
            af[i] = *(const short8*)(Ab + am * 64 + ((quad ^ ((am >> 1) & 3)) << 4));
        }
        __builtin_amdgcn_s_setprio(1);
        #pragma unroll
        for (int i = 0; i < 4; i++)
            #pragma unroll
            for (int j = 0; j < 4; j++)
                acc[i + 4][j] = __builtin_amdgcn_mfma_f32_16x16x32_bf16(af[i], bf[j], acc[i + 4][j], 0, 0, 0);
        __builtin_amdgcn_s_setprio(0);

        cur = (cur == 2) ? 0 : cur + 1;
        st  = (st  == 2) ? 0 : st  + 1;
    }

    // last tile (T=31): drain remaining 4 loads, no staging
    asm volatile("s_waitcnt vmcnt(0)" ::: "memory");
    __builtin_amdgcn_sched_barrier(0);
    __builtin_amdgcn_s_barrier();
    __builtin_amdgcn_sched_barrier(0);
    {
        const char* Ab = smem + cur * 32768;
        const char* Bb = Ab + 16384;
        #pragma unroll
        for (int j = 0; j < 4; j++) {
            int bn = wc * 64 + j * 16 + l16;
            bf[j] = *(const short8*)(Bb + bn * 64 + ((quad ^ ((bn >> 1) & 3)) << 4));
        }
        #pragma unroll
        for (int i = 0; i < 4; i++) {
            int am = wr * 128 + i * 16 + l16;
            af[i] = *(const short8*)(Ab + am * 64 + ((quad ^ ((am >> 1) & 3)) << 4));
        }
        #pragma unroll
        for (int i = 0; i < 4; i++)
            #pragma unroll
            for (int j = 0; j < 4; j++)
                acc[i][j] = __builtin_amdgcn_mfma_f32_16x16x32_bf16(af[i], bf[j], acc[i][j], 0, 0, 0);
        #pragma unroll
        for (int i = 0; i < 4; i++) {
            int am = wr * 128 + (i + 4) * 16 + l16;
            af[i] = *(const short8*)(Ab + am * 64 + ((quad ^ ((am >> 1) & 3)) << 4));
        }
        #pragma unroll
        for (int i = 0; i < 4; i++)
            #pragma unroll
            for (int j = 0; j < 4; j++)
                acc[i + 4][j] = __builtin_amdgcn_mfma_f32_16x16x32_bf16(af[i], bf[j], acc[i + 4][j], 0, 0, 0);
    }

    #pragma unroll
    for (int j = 0; j < 4; j++) {
        float bv = biasq[n0 + wc * 64 + j * 16 + l16];
        #pragma unroll
        for (int i = 0; i < 8; i++)
            #pragma unroll
            for (int r = 0; r < 4; r++) acc[i][j][r] += bv;
    }

    if (nt < 4) {
        #pragma unroll
        for (int j = 0; j < 4; j++) {
            int col = n0 + wc * 64 + j * 16 + l16;
            #pragma unroll
            for (int i = 0; i < 8; i++) {
                #pragma unroll
                for (int r = 0; r < 4; r++) {
                    int row = m0 + wr * 128 + i * 16 + quad * 4 + r;
                    Qb[(size_t)row * DM + col] = f2b(acc[i][j][r]);
                }
            }
        }
        return;
    }

    // ---- KV region (round-5/8 verified): cols [0,128)=head 2*(nt-4), [128,256)=+1
    // Xt overlay: col c (0..255) at byte c*512, row l at byte (l*2)^((c&7)<<4)
    __builtin_amdgcn_sched_barrier(0);
    __builtin_amdgcn_s_barrier();        // all waves done with staging buffers

    #pragma unroll
    for (int j = 0; j < 4; j++) {
        int c = wc * 64 + j * 16 + l16;
        int cs = (c & 7) << 4;
        #pragma unroll
        for (int i = 0; i < 8; i++) {
            int l0 = wr * 128 + i * 16 + quad * 4;
            uint2 o;
            o.x = (unsigned)f2b(acc[i][j][0]) | ((unsigned)f2b(acc[i][j][1]) << 16);
            o.y = (unsigned)f2b(acc[i][j][2]) | ((unsigned)f2b(acc[i][j][3]) << 16);
            *(uint2*)(smem + c * 512 + ((l0 * 2) ^ cs)) = o;
        }
    }
    __builtin_amdgcn_sched_barrier(0);
    __builtin_amdgcn_s_barrier();

    const int hh = w >> 2;            // head within tile (0,1)
    const int s  = w & 3;             // d1 slice (16 rows each)
    const int bb = mt >> 3;
    const int h  = (nt - 4) * 2 + hh;

    f32x4 kacc[4];
    #pragma unroll
    for (int j = 0; j < 4; j++)
        #pragma unroll
        for (int r = 0; r < 4; r++) kacc[j][r] = 0.f;

    #pragma unroll
    for (int ks = 0; ks < 8; ks++) {
        int ca = hh * 128 + s * 16 + l16;
        short8 afk = *(const short8*)(smem + ca * 512 + ((ks * 64 + quad * 16) ^ ((ca & 7) << 4)));
        #pragma unroll
        for (int j = 0; j < 4; j++) {
            int cb = hh * 128 + 64 + j * 16 + l16;
            short8 bfk = *(const short8*)(smem + cb * 512 + ((ks * 64 + quad * 16) ^ ((cb & 7) << 4)));
            kacc[j] = __builtin_amdgcn_mfma_f32_16x16x32_bf16(afk, bfk, kacc[j], 0, 0, 0);
        }
    }

    float* dst = KtV + (size_t)(bb * NH + h) * 64 * 64;
    #pragma unroll
    for (int j = 0; j < 4; j++) {
        int col = j * 16 + l16;
        #pragma unroll
        for (int r = 0; r < 4; r++) {
            int row = s * 16 + quad * 4 + r;
            atomicAdd(dst + row * 64 + col, kacc[j][r]);
        }
    }
}

// ---------------- ZT[b][n][h*64+d1] = sum_d2 KtV[bh][d1][d2]*WoT[n][h*64+d2] --
__global__ __launch_bounds__(256)
void zmat_kernel(const unsigned short* __restrict__ WoT, const float* __restrict__ KtV,
                 unsigned short* __restrict__ ZT)
{
    __shared__ __align__(16) unsigned short Asl[64][72];  // [n][d2]
    __shared__ __align__(16) unsigned short Bsl[64][72];  // [d1][d2]

    const int bh = blockIdx.x, nt0 = blockIdx.y;
    const int b = bh >> 4, h = bh & 15;
    const int t = threadIdx.x;
    const int wave = t >> 6, lane = t & 63;
    const int quad = lane >> 4, l16 = lane & 15;
    const int n0 = nt0 * 64;
    const int row = t >> 2, c0 = (t & 3) << 4;

    const unsigned short* ap = WoT + (size_t)(n0 + row) * DM + h * DH + c0;
    *(uint4*)&Asl[row][c0]     = *(const uint4*)ap;
    *(uint4*)&Asl[row][c0 + 8] = *(const uint4*)(ap + 8);

    const float* kp = KtV + ((size_t)bh * 64 + row) * 64 + c0;
    #pragma unroll
    for (int j = 0; j < 16; j++) Bsl[row][c0 + j] = f2b(kp[j]);
    __syncthreads();

    f32x4 acc[4];
    #pragma unroll
    for (int i = 0; i < 4; i++)
        #pragma unroll
        for (int r = 0; r < 4; r++) acc[i][r] = 0.f;

    #pragma unroll
    for (int ks = 0; ks < 2; ks++) {
        short8 af = *(const short8*)&Asl[wave * 16 + l16][ks * 32 + quad * 8];
        #pragma unroll
        for (int nt = 0; nt < 4; nt++) {
            short8 bfr = *(const short8*)&Bsl[nt * 16 + l16][ks * 32 + quad * 8];
            acc[nt] = __builtin_amdgcn_mfma_f32_16x16x32_bf16(af, bfr, acc[nt], 0, 0, 0);
        }
    }

    unsigned short* zb = ZT + (size_t)b * 1024 * 1024 + (size_t)h * DH;
    #pragma unroll
    for (int nt = 0; nt < 4; nt++) {
        int col = nt * 16 + l16;
        #pragma unroll
        for (int r = 0; r < 4; r++) {
            int zr = n0 + wave * 16 + quad * 4 + r;
            zb[(size_t)zr * 1024 + col] = f2b(acc[nt][r]);
        }
    }
}

// ---- out = Q @ ZT[b] + bo: 128x64 tile, BK=64, 3-buffer counted pipeline ----
__global__ __launch_bounds__(256)
void out_gemm_kernel(const unsigned short* __restrict__ A,
                     const unsigned short* __restrict__ Bt,
                     const float* __restrict__ bias,
                     float* __restrict__ C)
{
    __shared__ __align__(16) char smem[73728];
    // buffers 0..2 at b*24576: A-tile 128x64 bf16 (16 KB) + B-tile 64x64 (8 KB)

    const int bid = blockIdx.x;
    const int xcd = bid & 7, local = bid >> 3;   // 64 per XCD
    const int mt = xcd * 4 + (local & 3);        // 0..31
    const int nt = local >> 2;                   // 0..15
    const int m0 = mt * 128, n0 = nt * 64;

    const int t = threadIdx.x;
    const int w = t >> 6, lane = t & 63;
    const int quad = lane >> 4, l16 = lane & 15;

    const unsigned short* Btb = Bt + (size_t)(m0 >> 11) * 1024 * 1024;

    f32x4 acc[2][4];
    #pragma unroll
    for (int i = 0; i < 2; i++)
        #pragma unroll
        for (int j = 0; j < 4; j++)
            #pragma unroll
            for (int r = 0; r < 4; r++) acc[i][j][r] = 0.f;

    auto STAGE = [&](int buf, int kk) {
        #pragma unroll
        for (int p = 0; p < 4; p++) {              // A: 128 rows x 8 chunks
            int c = p * 256 + t;
            int row = c >> 3, slot = c & 7;
            int g = slot ^ ((row >> 1) & 7);
            gld_lds16(A + (size_t)(m0 + row) * DM + kk + g * 8,
                      smem + buf * 24576 + p * 4096 + w * 1024);
        }
        #pragma unroll
        for (int p = 0; p < 2; p++) {              // B: 64 rows x 8 chunks
            int c = p * 256 + t;
            int row = c >> 3, slot = c & 7;
            int g = slot ^ ((row >> 1) & 7);
            gld_lds16(Btb + (size_t)(n0 + row) * DM + kk + g * 8,
                      smem + buf * 24576 + 16384 + p * 4096 + w * 1024);
        }
    };
    auto COMPUTE = [&](int buf) {
        const char* Asb = smem + buf * 24576;
        const char* Bsb = Asb + 16384;
        #pragma unroll
        for (int ks = 0; ks < 2; ks++) {
            int kc = ks * 4 + quad;
            short8 afr[2], bfr[4];
            #pragma unroll
            for (int i = 0; i < 2; i++) {
                int am = w * 32 + i * 16 + l16;
                afr[i] = *(const short8*)(Asb + am * 128 + ((kc ^ ((am >> 1) & 7)) << 4));
            }
            #pragma unroll
            for (int j = 0; j < 4; j++) {
                int bn = j * 16 + l16;
                bfr[j] = *(const short8*)(Bsb + bn * 128 + ((kc ^ ((bn >> 1) & 7)) << 4));
            }
            __builtin_amdgcn_s_setprio(1);
            #pragma unroll
            for (int i = 0; i < 2; i++)
                #pragma unroll
                for (int j = 0; j < 4; j++)
                    acc[i][j] = __builtin_amdgcn_mfma_f32_16x16x32_bf16(afr[i], bfr[j], acc[i][j], 0, 0, 0);
            __builtin_amdgcn_s_setprio(0);
        }
    };

    // prologue: tiles 0,1 in flight (6 loads/thread each)
    STAGE(0, 0);
    STAGE(1, 64);

    int cur = 0, st = 2;
    // 16 K-tiles total: loop T=0..14 (stage tiles 2..15 while T<14), final T=15
    for (int T = 0; T < 15; T++) {
        asm volatile("s_waitcnt vmcnt(6)" ::: "memory");   // tile T landed
        __builtin_amdgcn_sched_barrier(0);
        __builtin_amdgcn_s_barrier();
        __builtin_amdgcn_sched_barrier(0);

        if (T < 14) STAGE(st, (T + 2) * 64);
        COMPUTE(cur);

        cur = (cur == 2) ? 0 : cur + 1;
        st  = (st  == 2) ? 0 : st  + 1;
    }
    // final tile (T=15): cur == 0 here (15 % 3)
    asm volatile("s_waitcnt vmcnt(0)" ::: "memory");
    __builtin_amdgcn_sched_barrier(0);
    __builtin_amdgcn_s_barrier();
    __builtin_amdgcn_sched_barrier(0);
    COMPUTE(cur);

    #pragma unroll
    for (int j = 0; j < 4; j++) {
        int col = n0 + j * 16 + l16;
        float bv = bias[col];
        #pragma unroll
        for (int i = 0; i < 2; i++) {
            #pragma unroll
            for (int r = 0; r < 4; r++) {
                int row = m0 + w * 32 + i * 16 + quad * 4 + r;
                C[(size_t)row * DM + col] = acc[i][j][r] + bv;
            }
        }
    }
}

// ---------------- launch ------------------------------------------------------

extern "C" void kernel_launch(void* const* d_in, const int* in_sizes, int n_in,
                              void* d_out, int out_size, void* d_ws, size_t ws_size,
                              hipStream_t stream)
{
    const float* x  = (const float*)d_in[0];
    const float* Wq = (const float*)d_in[1];
    const float* bq = (const float*)d_in[2];
    const float* Wk = (const float*)d_in[3];
    const float* bk = (const float*)d_in[4];
    const float* Wv = (const float*)d_in[5];
    const float* bv = (const float*)d_in[6];
    const float* Wo = (const float*)d_in[7];
    const float* bo = (const float*)d_in[8];

    char* ws = (char*)d_ws;
    unsigned short* xb    = (unsigned short*)(ws);                              // 8 MB
    unsigned short* WqkvT = (unsigned short*)(ws + (size_t)8  * 1024 * 1024);   // 6 MB
    unsigned short* WoT   = (unsigned short*)(ws + (size_t)14 * 1024 * 1024);   // 2 MB
    float*          biasq = (float*)         (ws + (size_t)16 * 1024 * 1024);   // 12 KB
    unsigned short* Qb    = (unsigned short*)(ws + (size_t)17 * 1024 * 1024);   // 8 MB
    unsigned short* ZT    = (unsigned short*)(ws + (size_t)25 * 1024 * 1024);   // 4 MB
    float*          KtV   = (float*)         (ws + (size_t)29 * 1024 * 1024);   // 512 KB

    setup_kernel<<<6284, 256, 0, stream>>>(x, Wq, Wk, Wv, Wo, bq, bk, bv,
                                           xb, WqkvT, WoT, biasq, KtV);

    qkv_fused_kernel<<<192, 512, 0, stream>>>(xb, WqkvT, biasq, Qb, KtV);

    zmat_kernel<<<dim3(B_ * NH, 16), 256, 0, stream>>>(WoT, KtV, ZT);

    out_gemm_kernel<<<512, 256, 0, stream>>>(Qb, ZT, bo, (float*)d_out);
}

// Round 14
// 138.113 us; speedup vs baseline: 1.0269x; 1.0267x over previous
//
#include <hip/hip_runtime.h>
#include <stdint.h>

#define B_ 2
#define L_ 2048
#define DM 1024
#define NH 16
#define DH 64
#define M_ (B_*L_)     // 4096

typedef short short8 __attribute__((ext_vector_type(8)));
typedef float f32x4 __attribute__((ext_vector_type(4)));

__device__ __forceinline__ unsigned short f2b(float f) {
    union { float f; unsigned int u; } v; v.f = f;
    unsigned int u = v.u;
    return (unsigned short)((u + 0x7fffu + ((u >> 16) & 1u)) >> 16);   // RNE
}

__device__ __forceinline__ void gld_lds16(const void* g, void* l) {
    __builtin_amdgcn_global_load_lds(
        (const __attribute__((address_space(1))) void*)g,
        (__attribute__((address_space(3))) void*)l, 16, 0, 0);
}

// ---------------- fused setup (round-0 proven) -------------------------------
__global__ __launch_bounds__(256)
void setup_kernel(const float* __restrict__ x,
                  const float* __restrict__ Wq, const float* __restrict__ Wk,
                  const float* __restrict__ Wv, const float* __restrict__ Wo,
                  const float* __restrict__ bq, const float* __restrict__ bk,
                  const float* __restrict__ bv,
                  unsigned short* __restrict__ xb, unsigned short* __restrict__ WqkvT,
                  unsigned short* __restrict__ WoT, float* __restrict__ biasq,
                  float* __restrict__ KtV)
{
    __shared__ float tile[32][33];
    const int bid = blockIdx.x;
    const int t = threadIdx.x;

    if (bid < 2048) {
        int i = (bid * 256 + t) * 8;
        float4 a0 = *(const float4*)(x + i);
        float4 a1 = *(const float4*)(x + i + 4);
        uint4 p;
        p.x = (unsigned)f2b(a0.x) | ((unsigned)f2b(a0.y) << 16);
        p.y = (unsigned)f2b(a0.z) | ((unsigned)f2b(a0.w) << 16);
        p.z = (unsigned)f2b(a1.x) | ((unsigned)f2b(a1.y) << 16);
        p.w = (unsigned)f2b(a1.z) | ((unsigned)f2b(a1.w) << 16);
        *(uint4*)(xb + i) = p;
    } else if (bid < 2048 + 4096) {
        int wb = bid - 2048;
        int wi = wb >> 10;                // 0=Wq 1=Wk 2=Wv 3=Wo
        int tid = wb & 1023;
        const float* W = (wi == 0) ? Wq : (wi == 1) ? Wk : (wi == 2) ? Wv : Wo;
        float s = (wi == 1) ? 0.125f : 1.0f;
        int n0 = (tid & 31) * 32, k0 = (tid >> 5) * 32;
        int r = t >> 3, c4 = (t & 7) << 2;
        float4 v = *(const float4*)(W + (size_t)(k0 + r) * DM + n0 + c4);
        tile[r][c4+0] = v.x; tile[r][c4+1] = v.y; tile[r][c4+2] = v.z; tile[r][c4+3] = v.w;
        __syncthreads();
        uint2 o;
        o.x = (unsigned)f2b(tile[c4+0][r]*s) | ((unsigned)f2b(tile[c4+1][r]*s) << 16);
        o.y = (unsigned)f2b(tile[c4+2][r]*s) | ((unsigned)f2b(tile[c4+3][r]*s) << 16);
        int f = n0 + r;
        size_t drow;
        unsigned short* dst;
        if (wi == 0)      { dst = WqkvT; drow = f; }
        else if (wi == 1) { dst = WqkvT; drow = 1024 + (f >> 6) * 128 + (f & 63); }
        else if (wi == 2) { dst = WqkvT; drow = 1024 + (f >> 6) * 128 + 64 + (f & 63); }
        else              { dst = WoT;   drow = f; }
        *(uint2*)(dst + drow * DM + k0 + c4) = o;
    } else if (bid < 2048 + 4096 + 12) {
        int n = (bid - 6144) * 256 + t;
        float v;
        if (n < 1024) v = bq[n];
        else {
            int kv = (n - 1024) >> 7, r = (n - 1024) & 127;
            v = (r < 64) ? 0.125f * bk[kv * 64 + r] : bv[kv * 64 + (r - 64)];
        }
        biasq[n] = v;
    } else {
        int i = ((bid - 6156) * 256 + t) * 4;
        float4 z; z.x = z.y = z.z = z.w = 0.f;
        *(float4*)(KtV + i) = z;
    }
}

// ---- QKV projection: 256x256 tile, 8 waves, BK=32, 3-buffer counted pipeline -
// grid: 192 blocks (mt 0..15, nt 0..11). nt<4 -> Q cols; nt>=4 -> 2 heads/tile
__global__ __launch_bounds__(512, 2)
void qkv_fused_kernel(const unsigned short* __restrict__ A,
                      const unsigned short* __restrict__ Bt,
                      const float* __restrict__ biasq,
                      unsigned short* __restrict__ Qb,
                      float* __restrict__ KtV)
{
    __shared__ __align__(16) char smem[131072];
    // buffers 0..2 at b*32768: A-tile 256x32 bf16 (16 KB) + B-tile (16 KB)
    // after K-loop: Xt overlay uses all 128 KB (KV blocks only)

    const int bid = blockIdx.x;
    const int mt = bid & 15;          // 0..15
    const int nt = bid >> 4;          // 0..11
    const int m0 = mt * 256, n0 = nt * 256;

    const int t = threadIdx.x;        // 0..511
    const int w = t >> 6, lane = t & 63;
    const int quad = lane >> 4, l16 = lane & 15;
    const int wr = w >> 2, wc = w & 3;   // wave output: rows wr*128+, cols wc*64+

    f32x4 acc[8][4];
    #pragma unroll
    for (int i = 0; i < 8; i++)
        #pragma unroll
        for (int j = 0; j < 4; j++)
            #pragma unroll
            for (int r = 0; r < 4; r++) acc[i][j][r] = 0.f;

    // per-thread staging map: 2 gld per matrix per tile
    const int c0 = t, c1 = 512 + t;
    const int row0 = c0 >> 2, g0 = (c0 & 3) ^ ((row0 >> 1) & 3);
    const int row1 = c1 >> 2, g1 = (c1 & 3) ^ ((row1 >> 1) & 3);

    auto STAGE_A = [&](int buf, int kk) {
        gld_lds16(A + (size_t)(m0 + row0) * DM + kk + g0 * 8,
                  smem + buf * 32768 + w * 1024);
        gld_lds16(A + (size_t)(m0 + row1) * DM + kk + g1 * 8,
                  smem + buf * 32768 + 8192 + w * 1024);
    };
    auto STAGE_B = [&](int buf, int kk) {
        gld_lds16(Bt + (size_t)(n0 + row0) * DM + kk + g0 * 8,
                  smem + buf * 32768 + 16384 + w * 1024);
        gld_lds16(Bt + (size_t)(n0 + row1) * DM + kk + g1 * 8,
                  smem + buf * 32768 + 16384 + 8192 + w * 1024);
    };

    // prologue: tiles 0,1 in flight (8 loads/thread); wait tile 0 (keep 4)
    STAGE_A(0, 0);  STAGE_B(0, 0);
    STAGE_A(1, 32); STAGE_B(1, 32);

    int cur = 0, st = 2;
    short8 bf[4], af[4];

    for (int T = 0; T < 31; T++) {
        asm volatile("s_waitcnt vmcnt(4)" ::: "memory");
        __builtin_amdgcn_sched_barrier(0);
        __builtin_amdgcn_s_barrier();
        __builtin_amdgcn_sched_barrier(0);

        const char* Ab = smem + cur * 32768;
        const char* Bb = Ab + 16384;

        // phase 0: stage A(T+2), read af0-3 + bf0-3, 16 MFMA
        if (T < 30) STAGE_A(st, (T + 2) * 32);
        #pragma unroll
        for (int j = 0; j < 4; j++) {
            int bn = wc * 64 + j * 16 + l16;
            bf[j] = *(const short8*)(Bb + bn * 64 + ((quad ^ ((bn >> 1) & 3)) << 4));
        }
        #pragma unroll
        for (int i = 0; i < 4; i++) {
            int am = wr * 128 + i * 16 + l16;
            af[i] = *(const short8*)(Ab + am * 64 + ((quad ^ ((am >> 1) & 3)) << 4));
        }
        __builtin_amdgcn_s_setprio(1);
        #pragma unroll
        for (int i = 0; i < 4; i++)
            #pragma unroll
            for (int j = 0; j < 4; j++)
                acc[i][j] = __builtin_amdgcn_mfma_f32_16x16x32_bf16(af[i], bf[j], acc[i][j], 0, 0, 0);
        __builtin_amdgcn_s_setprio(0);

        // phase 1: stage B(T+2), read af4-7, 16 MFMA
        if (T < 30) STAGE_B(st, (T + 2) * 32);
        #pragma unroll
        for (int i = 0; i < 4; i++) {
            int am = wr * 128 + (i + 4) * 16 + l16;
            af[i] = *(const short8*)(Ab + am * 64 + ((quad ^ ((am >> 1) & 3)) << 4));
        }
        __builtin_amdgcn_s_setprio(1);
        #pragma unroll
        for (int i = 0; i < 4; i++)
            #pragma unroll
            for (int j = 0; j < 4; j++)
                acc[i + 4][j] = __builtin_amdgcn_mfma_f32_16x16x32_bf16(af[i], bf[j], acc[i + 4][j], 0, 0, 0);
        __builtin_amdgcn_s_setprio(0);

        cur = (cur == 2) ? 0 : cur + 1;
        st  = (st  == 2) ? 0 : st  + 1;
    }

    // last tile (T=31): drain remaining 4 loads, no staging
    asm volatile("s_waitcnt vmcnt(0)" ::: "memory");
    __builtin_amdgcn_sched_barrier(0);
    __builtin_amdgcn_s_barrier();
    __builtin_amdgcn_sched_barrier(0);
    {
        const char* Ab = smem + cur * 32768;
        const char* Bb = Ab + 16384;
        #pragma unroll
        for (int j = 0; j < 4; j++) {
            int bn = wc * 64 + j * 16 + l16;
            bf[j] = *(const short8*)(Bb + bn * 64 + ((quad ^ ((bn >> 1) & 3)) << 4));
        }
        #pragma unroll
        for (int i = 0; i < 4; i++) {
            int am = wr * 128 + i * 16 + l16;
            af[i] = *(const short8*)(Ab + am * 64 + ((quad ^ ((am >> 1) & 3)) << 4));
        }
        #pragma unroll
        for (int i = 0; i < 4; i++)
            #pragma unroll
            for (int j = 0; j < 4; j++)
                acc[i][j] = __builtin_amdgcn_mfma_f32_16x16x32_bf16(af[i], bf[j], acc[i][j], 0, 0, 0);
        #pragma unroll
        for (int i = 0; i < 4; i++) {
            int am = wr * 128 + (i + 4) * 16 + l16;
            af[i] = *(const short8*)(Ab + am * 64 + ((quad ^ ((am >> 1) & 3)) << 4));
        }
        #pragma unroll
        for (int i = 0; i < 4; i++)
            #pragma unroll
            for (int j = 0; j < 4; j++)
                acc[i + 4][j] = __builtin_amdgcn_mfma_f32_16x16x32_bf16(af[i], bf[j], acc[i + 4][j], 0, 0, 0);
    }

    #pragma unroll
    for (int j = 0; j < 4; j++) {
        float bv = biasq[n0 + wc * 64 + j * 16 + l16];
        #pragma unroll
        for (int i = 0; i < 8; i++)
            #pragma unroll
            for (int r = 0; r < 4; r++) acc[i][j][r] += bv;
    }

    if (nt < 4) {
        #pragma unroll
        for (int j = 0; j < 4; j++) {
            int col = n0 + wc * 64 + j * 16 + l16;
            #pragma unroll
            for (int i = 0; i < 8; i++) {
                #pragma unroll
                for (int r = 0; r < 4; r++) {
                    int row = m0 + wr * 128 + i * 16 + quad * 4 + r;
                    Qb[(size_t)row * DM + col] = f2b(acc[i][j][r]);
                }
            }
        }
        return;
    }

    // ---- KV region (round-5/8 verified): cols [0,128)=head 2*(nt-4), [128,256)=+1
    // Xt overlay: col c (0..255) at byte c*512, row l at byte (l*2)^((c&7)<<4)
    __builtin_amdgcn_sched_barrier(0);
    __builtin_amdgcn_s_barrier();        // all waves done with staging buffers

    #pragma unroll
    for (int j = 0; j < 4; j++) {
        int c = wc * 64 + j * 16 + l16;
        int cs = (c & 7) << 4;
        #pragma unroll
        for (int i = 0; i < 8; i++) {
            int l0 = wr * 128 + i * 16 + quad * 4;
            uint2 o;
            o.x = (unsigned)f2b(acc[i][j][0]) | ((unsigned)f2b(acc[i][j][1]) << 16);
            o.y = (unsigned)f2b(acc[i][j][2]) | ((unsigned)f2b(acc[i][j][3]) << 16);
            *(uint2*)(smem + c * 512 + ((l0 * 2) ^ cs)) = o;
        }
    }
    __builtin_amdgcn_sched_barrier(0);
    __builtin_amdgcn_s_barrier();

    const int hh = w >> 2;            // head within tile (0,1)
    const int s  = w & 3;             // d1 slice (16 rows each)
    const int bb = mt >> 3;
    const int h  = (nt - 4) * 2 + hh;

    f32x4 kacc[4];
    #pragma unroll
    for (int j = 0; j < 4; j++)
        #pragma unroll
        for (int r = 0; r < 4; r++) kacc[j][r] = 0.f;

    #pragma unroll
    for (int ks = 0; ks < 8; ks++) {
        int ca = hh * 128 + s * 16 + l16;
        short8 afk = *(const short8*)(smem + ca * 512 + ((ks * 64 + quad * 16) ^ ((ca & 7) << 4)));
        #pragma unroll
        for (int j = 0; j < 4; j++) {
            int cb = hh * 128 + 64 + j * 16 + l16;
            short8 bfk = *(const short8*)(smem + cb * 512 + ((ks * 64 + quad * 16) ^ ((cb & 7) << 4)));
            kacc[j] = __builtin_amdgcn_mfma_f32_16x16x32_bf16(afk, bfk, kacc[j], 0, 0, 0);
        }
    }

    float* dst = KtV + (size_t)(bb * NH + h) * 64 * 64;
    #pragma unroll
    for (int j = 0; j < 4; j++) {
        int col = j * 16 + l16;
        #pragma unroll
        for (int r = 0; r < 4; r++) {
            int row = s * 16 + quad * 4 + r;
            atomicAdd(dst + row * 64 + col, kacc[j][r]);
        }
    }
}

// ---------------- ZT[b][n][h*64+d1] = sum_d2 KtV[bh][d1][d2]*WoT[n][h*64+d2] --
__global__ __launch_bounds__(256)
void zmat_kernel(const unsigned short* __restrict__ WoT, const float* __restrict__ KtV,
                 unsigned short* __restrict__ ZT)
{
    __shared__ __align__(16) unsigned short Asl[64][72];  // [n][d2]
    __shared__ __align__(16) unsigned short Bsl[64][72];  // [d1][d2]

    const int bh = blockIdx.x, nt0 = blockIdx.y;
    const int b = bh >> 4, h = bh & 15;
    const int t = threadIdx.x;
    const int wave = t >> 6, lane = t & 63;
    const int quad = lane >> 4, l16 = lane & 15;
    const int n0 = nt0 * 64;
    const int row = t >> 2, c0 = (t & 3) << 4;

    const unsigned short* ap = WoT + (size_t)(n0 + row) * DM + h * DH + c0;
    *(uint4*)&Asl[row][c0]     = *(const uint4*)ap;
    *(uint4*)&Asl[row][c0 + 8] = *(const uint4*)(ap + 8);

    const float* kp = KtV + ((size_t)bh * 64 + row) * 64 + c0;
    #pragma unroll
    for (int j = 0; j < 16; j++) Bsl[row][c0 + j] = f2b(kp[j]);
    __syncthreads();

    f32x4 acc[4];
    #pragma unroll
    for (int i = 0; i < 4; i++)
        #pragma unroll
        for (int r = 0; r < 4; r++) acc[i][r] = 0.f;

    #pragma unroll
    for (int ks = 0; ks < 2; ks++) {
        short8 af = *(const short8*)&Asl[wave * 16 + l16][ks * 32 + quad * 8];
        #pragma unroll
        for (int nt = 0; nt < 4; nt++) {
            short8 bfr = *(const short8*)&Bsl[nt * 16 + l16][ks * 32 + quad * 8];
            acc[nt] = __builtin_amdgcn_mfma_f32_16x16x32_bf16(af, bfr, acc[nt], 0, 0, 0);
        }
    }

    unsigned short* zb = ZT + (size_t)b * 1024 * 1024 + (size_t)h * DH;
    #pragma unroll
    for (int nt = 0; nt < 4; nt++) {
        int col = nt * 16 + l16;
        #pragma unroll
        for (int r = 0; r < 4; r++) {
            int zr = n0 + wave * 16 + quad * 4 + r;
            zb[(size_t)zr * 1024 + col] = f2b(acc[nt][r]);
        }
    }
}

// ---- out = Q @ ZT[b] + bo: 128x64 tile, BK=64, 3-buffer counted pipeline ----
__global__ __launch_bounds__(256)
void out_gemm_kernel(const unsigned short* __restrict__ A,
                     const unsigned short* __restrict__ Bt,
                     const float* __restrict__ bias,
                     float* __restrict__ C)
{
    __shared__ __align__(16) char smem[73728];
    // buffers 0..2 at b*24576: A-tile 128x64 bf16 (16 KB) + B-tile 64x64 (8 KB)

    const int bid = blockIdx.x;
    const int xcd = bid & 7, local = bid >> 3;   // 64 per XCD
    const int mt = xcd * 4 + (local & 3);        // 0..31
    const int nt = local >> 2;                   // 0..15
    const int m0 = mt * 128, n0 = nt * 64;

    const int t = threadIdx.x;
    const int w = t >> 6, lane = t & 63;
    const int quad = lane >> 4, l16 = lane & 15;

    const unsigned short* Btb = Bt + (size_t)(m0 >> 11) * 1024 * 1024;

    f32x4 acc[2][4];
    #pragma unroll
    for (int i = 0; i < 2; i++)
        #pragma unroll
        for (int j = 0; j < 4; j++)
            #pragma unroll
            for (int r = 0; r < 4; r++) acc[i][j][r] = 0.f;

    auto STAGE = [&](int buf, int kk) {
        #pragma unroll
        for (int p = 0; p < 4; p++) {              // A: 128 rows x 8 chunks
            int c = p * 256 + t;
            int row = c >> 3, slot = c & 7;
            int g = slot ^ ((row >> 1) & 7);
            gld_lds16(A + (size_t)(m0 + row) * DM + kk + g * 8,
                      smem + buf * 24576 + p * 4096 + w * 1024);
        }
        #pragma unroll
        for (int p = 0; p < 2; p++) {              // B: 64 rows x 8 chunks
            int c = p * 256 + t;
            int row = c >> 3, slot = c & 7;
            int g = slot ^ ((row >> 1) & 7);
            gld_lds16(Btb + (size_t)(n0 + row) * DM + kk + g * 8,
                      smem + buf * 24576 + 16384 + p * 4096 + w * 1024);
        }
    };
    auto COMPUTE = [&](int buf) {
        const char* Asb = smem + buf * 24576;
        const char* Bsb = Asb + 16384;
        #pragma unroll
        for (int ks = 0; ks < 2; ks++) {
            int kc = ks * 4 + quad;
            short8 afr[2], bfr[4];
            #pragma unroll
            for (int i = 0; i < 2; i++) {
                int am = w * 32 + i * 16 + l16;
                afr[i] = *(const short8*)(Asb + am * 128 + ((kc ^ ((am >> 1) & 7)) << 4));
            }
            #pragma unroll
            for (int j = 0; j < 4; j++) {
                int bn = j * 16 + l16;
                bfr[j] = *(const short8*)(Bsb + bn * 128 + ((kc ^ ((bn >> 1) & 7)) << 4));
            }
            __builtin_amdgcn_s_setprio(1);
            #pragma unroll
            for (int i = 0; i < 2; i++)
                #pragma unroll
                for (int j = 0; j < 4; j++)
                    acc[i][j] = __builtin_amdgcn_mfma_f32_16x16x32_bf16(afr[i], bfr[j], acc[i][j], 0, 0, 0);
            __builtin_amdgcn_s_setprio(0);
        }
    };

    // prologue: tiles 0,1 in flight (6 loads/thread each)
    STAGE(0, 0);
    STAGE(1, 64);

    int cur = 0, st = 2;
    // 16 K-tiles total: loop T=0..14 (stage tiles 2..15 while T<14), final T=15
    for (int T = 0; T < 15; T++) {
        asm volatile("s_waitcnt vmcnt(6)" ::: "memory");   // tile T landed
        __builtin_amdgcn_sched_barrier(0);
        __builtin_amdgcn_s_barrier();
        __builtin_amdgcn_sched_barrier(0);

        if (T < 14) STAGE(st, (T + 2) * 64);
        COMPUTE(cur);

        cur = (cur == 2) ? 0 : cur + 1;
        st  = (st  == 2) ? 0 : st  + 1;
    }
    // final tile (T=15): cur == 0 here (15 % 3)
    asm volatile("s_waitcnt vmcnt(0)" ::: "memory");
    __builtin_amdgcn_sched_barrier(0);
    __builtin_amdgcn_s_barrier();
    __builtin_amdgcn_sched_barrier(0);
    COMPUTE(cur);

    #pragma unroll
    for (int j = 0; j < 4; j++) {
        int col = n0 + j * 16 + l16;
        float bv = bias[col];
        #pragma unroll
        for (int i = 0; i < 2; i++) {
            #pragma unroll
            for (int r = 0; r < 4; r++) {
                int row = m0 + w * 32 + i * 16 + quad * 4 + r;
                C[(size_t)row * DM + col] = acc[i][j][r] + bv;
            }
        }
    }
}

// ---------------- launch ------------------------------------------------------

extern "C" void kernel_launch(void* const* d_in, const int* in_sizes, int n_in,
                              void* d_out, int out_size, void* d_ws, size_t ws_size,
                              hipStream_t stream)
{
    const float* x  = (const float*)d_in[0];
    const float* Wq = (const float*)d_in[1];
    const float* bq = (const float*)d_in[2];
    const float* Wk = (const float*)d_in[3];
    const float* bk = (const float*)d_in[4];
    const float* Wv = (const float*)d_in[5];
    const float* bv = (const float*)d_in[6];
    const float* Wo = (const float*)d_in[7];
    const float* bo = (const float*)d_in[8];

    char* ws = (char*)d_ws;
    unsigned short* xb    = (unsigned short*)(ws);                              // 8 MB
    unsigned short* WqkvT = (unsigned short*)(ws + (size_t)8  * 1024 * 1024);   // 6 MB
    unsigned short* WoT   = (unsigned short*)(ws + (size_t)14 * 1024 * 1024);   // 2 MB
    float*          biasq = (float*)         (ws + (size_t)16 * 1024 * 1024);   // 12 KB
    unsigned short* Qb    = (unsigned short*)(ws + (size_t)17 * 1024 * 1024);   // 8 MB
    unsigned short* ZT    = (unsigned short*)(ws + (size_t)25 * 1024 * 1024);   // 4 MB
    float*          KtV   = (float*)         (ws + (size_t)29 * 1024 * 1024);   // 512 KB

    setup_kernel<<<6284, 256, 0, stream>>>(x, Wq, Wk, Wv, Wo, bq, bk, bv,
                                           xb, WqkvT, WoT, biasq, KtV);

    qkv_fused_kernel<<<192, 512, 0, stream>>>(xb, WqkvT, biasq, Qb, KtV);

    zmat_kernel<<<dim3(B_ * NH, 16), 256, 0, stream>>>(WoT, KtV, ZT);

    out_gemm_kernel<<<512, 256, 0, stream>>>(Qb, ZT, bo, (float*)d_out);
}